// Round 14
// baseline (597.220 us; speedup 1.0000x reference)
//
#include <hip/hip_runtime.h>
#include <hip/hip_bf16.h>

// DepthRouteNet — round 13: fc MFMA kernel re-tiled to 128x256 block /
// 64x128 per wave (4x8 frags): 12 ds_read_b128 per 32 MFMA (balanced) vs
// old 8 per 16 (LDS-bound). Split kernels / rest unchanged from R13.

typedef unsigned short u16;
typedef __attribute__((ext_vector_type(8))) short bf16x8;
typedef _Float16 f16x8 __attribute__((ext_vector_type(8)));
typedef __attribute__((ext_vector_type(4))) float f32x4;

__device__ inline float bf2f(u16 u) {
    union { unsigned int i; float f; } v; v.i = ((unsigned int)u) << 16; return v.f;
}
__device__ inline u16 f2bf(float f) {
    union { float f; unsigned int i; } v; v.f = f;
    unsigned int x = v.i;
    return (u16)((x + 0x7FFFu + ((x >> 16) & 1u)) >> 16);   // RNE
}

// ---------------- split-f16 MFMA GEMM (routing path; unchanged) --------------
template<int AMODE, bool RELU_OUT, bool MUL_EPI, bool DUAL>
__global__ __launch_bounds__(256, 2) void mfma_split_kernel(
    const float* __restrict__ A, const float* __restrict__ emp,
    const float* __restrict__ emW0, const float* __restrict__ emb0,
    const _Float16* __restrict__ BTh, const _Float16* __restrict__ BTl,
    const float* __restrict__ bias, const float* __restrict__ MulM,
    float* __restrict__ C, u16* __restrict__ Drelu, int M, int N, int K)
{
    __shared__ _Float16 Ah[128 * 40], Al[128 * 40];
    __shared__ _Float16 Bh[128 * 40], Bl[128 * 40];

    const int tid = threadIdx.x;
    const int wave = tid >> 6, lane = tid & 63;
    const int id = blockIdx.y * gridDim.x + blockIdx.x;
    const int nM = gridDim.y;
    const int m0 = (id % nM) * 128, n0 = (id / nM) * 128;
    const int quad = lane >> 4, l16 = lane & 15;
    const int mq = (wave >> 1) * 64, nq = (wave & 1) * 64;

    const int srow = tid >> 1;
    const int shf  = (tid & 1) * 16;

    f32x4 acch[4][4] = {};
    f32x4 accl[4][4] = {};

    for (int k0 = 0; k0 < K; k0 += 32) {
        {
            int ra = m0 + srow; if (ra >= M) ra = M - 1;
            float v[16];
            if constexpr (AMODE == 0) {
#pragma unroll
                for (int s = 0; s < 4; ++s) {
                    float4 q = *(const float4*)&A[(size_t)ra * K + k0 + shf + s * 4];
                    v[s*4+0] = q.x; v[s*4+1] = q.y; v[s*4+2] = q.z; v[s*4+3] = q.w;
                }
            } else {
                float emv = emp[ra];
#pragma unroll
                for (int s = 0; s < 4; ++s) {
                    float4 w = *(const float4*)&emW0[k0 + shf + s * 4];
                    float4 b = *(const float4*)&emb0[k0 + shf + s * 4];
                    v[s*4+0] = fmaxf(emv * w.x + b.x, 0.f);
                    v[s*4+1] = fmaxf(emv * w.y + b.y, 0.f);
                    v[s*4+2] = fmaxf(emv * w.z + b.z, 0.f);
                    v[s*4+3] = fmaxf(emv * w.w + b.w, 0.f);
                }
            }
            f16x8 h0, h1, l0, l1;
#pragma unroll
            for (int e = 0; e < 8; ++e) {
                _Float16 h = (_Float16)v[e];
                h0[e] = h; l0[e] = (_Float16)((v[e] - (float)h) * 2048.0f);
            }
#pragma unroll
            for (int e = 0; e < 8; ++e) {
                _Float16 h = (_Float16)v[8 + e];
                h1[e] = h; l1[e] = (_Float16)((v[8 + e] - (float)h) * 2048.0f);
            }
            *(f16x8*)&Ah[srow * 40 + shf]     = h0;
            *(f16x8*)&Ah[srow * 40 + shf + 8] = h1;
            *(f16x8*)&Al[srow * 40 + shf]     = l0;
            *(f16x8*)&Al[srow * 40 + shf + 8] = l1;
        }
        {
            size_t boff = (size_t)(n0 + srow) * K + k0 + shf;
            *(f16x8*)&Bh[srow * 40 + shf]     = *(const f16x8*)&BTh[boff];
            *(f16x8*)&Bh[srow * 40 + shf + 8] = *(const f16x8*)&BTh[boff + 8];
            *(f16x8*)&Bl[srow * 40 + shf]     = *(const f16x8*)&BTl[boff];
            *(f16x8*)&Bl[srow * 40 + shf + 8] = *(const f16x8*)&BTl[boff + 8];
        }
        __syncthreads();

        f16x8 afh[4], afl[4], bfh[4], bfl[4];
#pragma unroll
        for (int i = 0; i < 4; ++i) {
            afh[i] = *(const f16x8*)&Ah[(mq + i * 16 + l16) * 40 + quad * 8];
            afl[i] = *(const f16x8*)&Al[(mq + i * 16 + l16) * 40 + quad * 8];
        }
#pragma unroll
        for (int j = 0; j < 4; ++j) {
            bfh[j] = *(const f16x8*)&Bh[(nq + j * 16 + l16) * 40 + quad * 8];
            bfl[j] = *(const f16x8*)&Bl[(nq + j * 16 + l16) * 40 + quad * 8];
        }
#pragma unroll
        for (int i = 0; i < 4; ++i)
#pragma unroll
            for (int j = 0; j < 4; ++j) {
                acch[i][j] = __builtin_amdgcn_mfma_f32_16x16x32_f16(afh[i], bfh[j], acch[i][j], 0, 0, 0);
                accl[i][j] = __builtin_amdgcn_mfma_f32_16x16x32_f16(afh[i], bfl[j], accl[i][j], 0, 0, 0);
                accl[i][j] = __builtin_amdgcn_mfma_f32_16x16x32_f16(afl[i], bfh[j], accl[i][j], 0, 0, 0);
            }
        __syncthreads();
    }

    const float S = 1.0f / 2048.0f;
#pragma unroll
    for (int i = 0; i < 4; ++i) {
#pragma unroll
        for (int j = 0; j < 4; ++j) {
            int col = n0 + nq + j * 16 + l16;
            float bv = bias[col];
#pragma unroll
            for (int r = 0; r < 4; ++r) {
                int row = m0 + mq + i * 16 + quad * 4 + r;
                if (row < M) {
                    float v = acch[i][j][r] + accl[i][j][r] * S + bv;
                    if (RELU_OUT) v = fmaxf(v, 0.f);
                    if (MUL_EPI)  v *= MulM[(size_t)row * N + col];
                    C[(size_t)row * N + col] = v;
                    if (DUAL) Drelu[(size_t)row * N + col] = f2bf(fmaxf(v, 0.f));
                }
            }
        }
    }
}

// ---------------- MFMA bf16 GEMM for fc layers: 128x256 tile, 64x128/wave ----
// Requires N % 256 == 0. CMODE: 0 plain; 1 g0*A+g1*o1; 2 +g2*o2
template<int CMODE>
__global__ __launch_bounds__(256) void mfma_fc_kernel(
    const short* __restrict__ A, const short* __restrict__ o1p,
    const short* __restrict__ o2p, const float* __restrict__ gates, int goff,
    const short* __restrict__ BT, const float* __restrict__ bias,
    short* __restrict__ C, int M, int N, int K)
{
    __shared__ short As[128 * 40];   // 10 KB
    __shared__ short Bs[256 * 40];   // 20 KB
    const int tid = threadIdx.x;
    const int wave = tid >> 6, lane = tid & 63;
    const int id = blockIdx.y * gridDim.x + blockIdx.x;
    const int nM = gridDim.y;
    const int m0 = (id % nM) * 128, n0 = (id / nM) * 256;
    const int quad = lane >> 4, l16 = lane & 15;
    const int mq = (wave & 1) * 64, nq = (wave >> 1) * 128;

    f32x4 acc[4][8] = {};

    for (int k0 = 0; k0 < K; k0 += 32) {
        // ---- stage A 128x32 (512 chunks of 8) with optional combine ----
#pragma unroll
        for (int it = 0; it < 2; ++it) {
            int c = it * 256 + tid;
            int row = c >> 2, seg = c & 3;
            int ra = m0 + row; if (ra >= M) ra = M - 1;
            bf16x8 va = *(const bf16x8*)&A[(size_t)ra * K + k0 + seg * 8];
            if constexpr (CMODE > 0) {
                const float* gp = gates + (size_t)ra * 10 + goff;
                float g0 = gp[0], g1 = gp[1];
                bf16x8 v1 = *(const bf16x8*)&o1p[(size_t)ra * K + k0 + seg * 8];
                float g2 = 0.f; bf16x8 v2;
                if constexpr (CMODE == 2) {
                    g2 = gp[2];
                    v2 = *(const bf16x8*)&o2p[(size_t)ra * K + k0 + seg * 8];
                }
#pragma unroll
                for (int e = 0; e < 8; ++e) {
                    float f = g0 * bf2f((u16)va[e]) + g1 * bf2f((u16)v1[e]);
                    if constexpr (CMODE == 2) f += g2 * bf2f((u16)v2[e]);
                    va[e] = (short)f2bf(f);
                }
            }
            *(bf16x8*)&As[row * 40 + seg * 8] = va;
        }
        // ---- stage B 256x32 (1024 chunks of 8) ----
#pragma unroll
        for (int it = 0; it < 4; ++it) {
            int c = it * 256 + tid;
            int row = c >> 2, seg = c & 3;
            *(bf16x8*)&Bs[row * 40 + seg * 8] =
                *(const bf16x8*)&BT[(size_t)(n0 + row) * K + k0 + seg * 8];
        }
        __syncthreads();

        bf16x8 af[4], bfr[8];
#pragma unroll
        for (int i = 0; i < 4; ++i)
            af[i] = *(const bf16x8*)&As[(mq + i * 16 + l16) * 40 + quad * 8];
#pragma unroll
        for (int j = 0; j < 8; ++j)
            bfr[j] = *(const bf16x8*)&Bs[(nq + j * 16 + l16) * 40 + quad * 8];
#pragma unroll
        for (int i = 0; i < 4; ++i)
#pragma unroll
            for (int j = 0; j < 8; ++j)
                acc[i][j] = __builtin_amdgcn_mfma_f32_16x16x32_bf16(af[i], bfr[j], acc[i][j], 0, 0, 0);
        __syncthreads();
    }

#pragma unroll
    for (int i = 0; i < 4; ++i) {
#pragma unroll
        for (int j = 0; j < 8; ++j) {
            int col = n0 + nq + j * 16 + l16;
            float bv = bias[col];
#pragma unroll
            for (int r = 0; r < 4; ++r) {
                int row = m0 + mq + i * 16 + quad * 4 + r;
                if (row < M) {
                    float v = fmaxf(acc[i][j][r] + bv, 0.f);
                    C[(size_t)row * N + col] = (short)f2bf(v);
                }
            }
        }
    }
}

// ---------------- small-N GEMM (logits N=10, final N=18) ---------------------
template<int NN, bool ABF16, bool BBF16>
__global__ __launch_bounds__(256) void smallN_kernel(
    const void* __restrict__ Av, const float* __restrict__ Bw,
    const float* __restrict__ bias, float* __restrict__ C, int M, int K)
{
    extern __shared__ char smem[];
    const int tid = threadIdx.x;
    const int total = K * NN;
    if (BBF16) {
        u16* Bs = (u16*)smem;
        for (int i = tid; i < total; i += 256) Bs[i] = f2bf(Bw[i]);
    } else {
        float* Bs = (float*)smem;
        for (int i = tid; i < total; i += 256) Bs[i] = Bw[i];
    }
    __syncthreads();

    const int lane = tid & 63;
    const int wave = tid >> 6;
    const int l16 = lane & 15;
    const int rsub = lane >> 4;
    int row = blockIdx.x * 16 + wave * 4 + rsub;
    const bool valid = (row < M);
    if (row >= M) row = M - 1;

    float acc[NN];
#pragma unroll
    for (int j = 0; j < NN; ++j) acc[j] = 0.f;

    const int chunk = K >> 4;
    const int kbeg = l16 * chunk;

    if (ABF16) {
        const u16* A = (const u16*)Av + (size_t)row * K + kbeg;
        const u16* Bs = (const u16*)smem;
        for (int kk = 0; kk < chunk; kk += 4) {
            ushort4 u = *(const ushort4*)&A[kk];
            float a4[4] = {bf2f(u.x), bf2f(u.y), bf2f(u.z), bf2f(u.w)};
#pragma unroll
            for (int e = 0; e < 4; ++e) {
                const u16* bp = &Bs[(size_t)(kbeg + kk + e) * NN];
#pragma unroll
                for (int j = 0; j < NN; ++j) acc[j] += a4[e] * bf2f(bp[j]);
            }
        }
    } else {
        const float* A = (const float*)Av + (size_t)row * K + kbeg;
        const float* Bs = (const float*)smem;
        for (int kk = 0; kk < chunk; kk += 4) {
            float4 q = *(const float4*)&A[kk];
            float a4[4] = {q.x, q.y, q.z, q.w};
#pragma unroll
            for (int e = 0; e < 4; ++e) {
                const float* bp = &Bs[(size_t)(kbeg + kk + e) * NN];
#pragma unroll
                for (int j = 0; j < NN; ++j) acc[j] += a4[e] * bp[j];
            }
        }
    }

#pragma unroll
    for (int j = 0; j < NN; ++j) {
        float v = acc[j];
        v += __shfl_xor(v, 1, 16);
        v += __shfl_xor(v, 2, 16);
        v += __shfl_xor(v, 4, 16);
        v += __shfl_xor(v, 8, 16);
        acc[j] = v;
    }
    if (valid && l16 == 0) {
#pragma unroll
        for (int j = 0; j < NN; ++j)
            C[(size_t)row * NN + j] = acc[j] + bias[j];
    }
}

// ---------------- f32 64-tile GEMM (fallback) --------------------------------
template<int AMODE, bool OUT_BF16>
__global__ __launch_bounds__(256) void gemm_kernel(
    const void* __restrict__ Av, const float* __restrict__ Bw,
    const float* __restrict__ bias, void* __restrict__ Cv, int M, int N, int K)
{
    __shared__ float As[16][68];
    __shared__ float Bs[16][64];

    const int tid = threadIdx.x;
    const int tx = tid & 15, ty = tid >> 4;
    const int m0 = blockIdx.y * 64;
    const int n0 = blockIdx.x * 64;

    const int arow = tid >> 2;
    const int ak   = (tid & 3) * 4;
    const int brow = tid >> 4;
    const int bcol = (tid & 15) * 4;

    float acc[4][4];
#pragma unroll
    for (int i = 0; i < 4; i++)
#pragma unroll
        for (int j = 0; j < 4; j++) acc[i][j] = 0.f;

    for (int k0 = 0; k0 < K; k0 += 16) {
        float4 av;
        int r = m0 + arow; if (r >= M) r = M - 1;
        if constexpr (AMODE == 0) {
            av = *(const float4*)((const float*)Av + (size_t)r * K + (k0 + ak));
        } else {
            ushort4 u = *(const ushort4*)((const u16*)Av + (size_t)r * K + (k0 + ak));
            av.x = bf2f(u.x); av.y = bf2f(u.y); av.z = bf2f(u.z); av.w = bf2f(u.w);
        }
        As[ak + 0][arow] = av.x; As[ak + 1][arow] = av.y;
        As[ak + 2][arow] = av.z; As[ak + 3][arow] = av.w;

#pragma unroll
        for (int j = 0; j < 4; j++) {
            int c = n0 + bcol + j;
            Bs[brow][bcol + j] = (c < N) ? Bw[(size_t)(k0 + brow) * N + c] : 0.f;
        }
        __syncthreads();

#pragma unroll
        for (int kk = 0; kk < 16; kk++) {
            float4 a = *(const float4*)&As[kk][ty * 4];
            float4 b = *(const float4*)&Bs[kk][tx * 4];
            acc[0][0] += a.x * b.x; acc[0][1] += a.x * b.y; acc[0][2] += a.x * b.z; acc[0][3] += a.x * b.w;
            acc[1][0] += a.y * b.x; acc[1][1] += a.y * b.y; acc[1][2] += a.y * b.z; acc[1][3] += a.y * b.w;
            acc[2][0] += a.z * b.x; acc[2][1] += a.z * b.y; acc[2][2] += a.z * b.z; acc[2][3] += a.z * b.w;
            acc[3][0] += a.w * b.x; acc[3][1] += a.w * b.y; acc[3][2] += a.w * b.z; acc[3][3] += a.w * b.w;
        }
        __syncthreads();
    }

#pragma unroll
    for (int i = 0; i < 4; i++) {
        int r = m0 + ty * 4 + i;
#pragma unroll
        for (int j = 0; j < 4; j++) {
            int c = n0 + tx * 4 + j;
            if (r < M && c < N) {
                float v = acc[i][j] + bias[c];
                if (OUT_BF16) ((u16*)Cv)[(size_t)r * N + c] = f2bf(v);
                else          ((float*)Cv)[(size_t)r * N + c] = v;
            }
        }
    }
}

// transpose + f32->bf16: in [K,N] f32 -> out [N,K] bf16. K,N % 64 == 0.
__global__ __launch_bounds__(256) void transpose_kernel(
    const float* __restrict__ in, u16* __restrict__ out, int K, int N)
{
    __shared__ u16 T[64][65];
    int k0 = blockIdx.y * 64, n0 = blockIdx.x * 64;
    int t = threadIdx.x;
    int r = t >> 4, c4 = (t & 15) * 4;
#pragma unroll
    for (int i = 0; i < 4; ++i) {
        int kk = r + i * 16;
        float4 v = *(const float4*)&in[(size_t)(k0 + kk) * N + n0 + c4];
        T[c4 + 0][kk] = f2bf(v.x); T[c4 + 1][kk] = f2bf(v.y);
        T[c4 + 2][kk] = f2bf(v.z); T[c4 + 3][kk] = f2bf(v.w);
    }
    __syncthreads();
#pragma unroll
    for (int i = 0; i < 4; ++i) {
        int nn = r + i * 16;
        ushort4 o;
        o.x = T[nn][c4 + 0]; o.y = T[nn][c4 + 1];
        o.z = T[nn][c4 + 2]; o.w = T[nn][c4 + 3];
        *(ushort4*)&out[(size_t)(n0 + nn) * K + k0 + c4] = o;
    }
}

// transpose + f16 hi/lo split: in [K,N] f32 -> hi/lo f16 [N,K]. K,N % 64 == 0.
__global__ __launch_bounds__(256) void transpose_split_kernel(
    const float* __restrict__ in, u16* __restrict__ outh, u16* __restrict__ outl,
    int K, int N)
{
    __shared__ u16 Th[64][65];
    __shared__ u16 Tl[64][65];
    int k0 = blockIdx.y * 64, n0 = blockIdx.x * 64;
    int t = threadIdx.x;
    int r = t >> 4, c4 = (t & 15) * 4;
    union { _Float16 h; u16 u; } cv;
#pragma unroll
    for (int i = 0; i < 4; ++i) {
        int kk = r + i * 16;
        float4 v = *(const float4*)&in[(size_t)(k0 + kk) * N + n0 + c4];
        float vv[4] = {v.x, v.y, v.z, v.w};
#pragma unroll
        for (int e = 0; e < 4; ++e) {
            _Float16 h = (_Float16)vv[e];
            cv.h = h; Th[c4 + e][kk] = cv.u;
            cv.h = (_Float16)((vv[e] - (float)h) * 2048.0f);
            Tl[c4 + e][kk] = cv.u;
        }
    }
    __syncthreads();
#pragma unroll
    for (int i = 0; i < 4; ++i) {
        int nn = r + i * 16;
        ushort4 oh, ol;
        oh.x = Th[nn][c4 + 0]; oh.y = Th[nn][c4 + 1];
        oh.z = Th[nn][c4 + 2]; oh.w = Th[nn][c4 + 3];
        ol.x = Tl[nn][c4 + 0]; ol.y = Tl[nn][c4 + 1];
        ol.z = Tl[nn][c4 + 2]; ol.w = Tl[nn][c4 + 3];
        *(ushort4*)&outh[(size_t)(n0 + nn) * K + k0 + c4] = oh;
        *(ushort4*)&outl[(size_t)(n0 + nn) * K + k0 + c4] = ol;
    }
}

__global__ __launch_bounds__(256) void routing_kernel(
    const float* __restrict__ logits, int Bc,
    float* __restrict__ gates, float* __restrict__ onehot,
    float* __restrict__ soft)
{
    int b = blockIdx.x * blockDim.x + threadIdx.x;
    if (b >= Bc) return;
    const float* l = logits + (size_t)b * 10;
    float* g  = gates  + (size_t)b * 10;
    float* oh = onehot + (size_t)b * 10;
    float* sf = soft   + (size_t)b * 10;

    g[0] = 1.f; oh[0] = 1.f; sf[0] = 1.f;

    int off = 1;
    for (int m = 2; m <= 4; m++) {
        float v[4];
        for (int i = 0; i < m; i++) v[i] = l[off + i];
        int i0 = 0;
        for (int i = 1; i < m; i++) if (v[i] > v[i0]) i0 = i;
        int i1 = (i0 == 0) ? 1 : 0;
        for (int i = 0; i < m; i++) if (i != i0 && v[i] > v[i1]) i1 = i;
        float e1 = expf(v[i1] - v[i0]);
        float inv = 1.f / (1.f + e1);
        for (int i = 0; i < m; i++) { g[off + i] = 0.f; oh[off + i] = 0.f; }
        g[off + i0] = inv;
        g[off + i1] = e1 * inv;
        oh[off + i0] = 1.f; oh[off + i1] = 1.f;
        float mall = v[0];
        for (int i = 1; i < m; i++) mall = fmaxf(mall, v[i]);
        float ex[4]; float se = 0.f;
        for (int i = 0; i < m; i++) { ex[i] = expf(v[i] - mall); se += ex[i]; }
        float rse = 1.f / se;
        for (int i = 0; i < m; i++) sf[off + i] = ex[i] * rse;
        off += m;
    }
}

__global__ __launch_bounds__(256) void combine_kernel(
    const float* __restrict__ gates, int goff, int n4, int H,
    const u16* __restrict__ o0, const u16* __restrict__ o1,
    const u16* __restrict__ o2, const u16* __restrict__ o3,
    u16* __restrict__ dst)
{
    int i4 = blockIdx.x * blockDim.x + threadIdx.x;
    if (i4 >= n4) return;
    int b = (i4 * 4) / H;
    const float* gp = gates + (size_t)b * 10 + goff;
    float g0 = gp[0], g1 = gp[1], g2 = gp[2], g3 = gp[3];
    ushort4 a  = ((const ushort4*)o0)[i4];
    ushort4 u1 = ((const ushort4*)o1)[i4];
    ushort4 u2 = ((const ushort4*)o2)[i4];
    ushort4 u3 = ((const ushort4*)o3)[i4];
    float4 acc;
    acc.x = g0 * bf2f(a.x) + g1 * bf2f(u1.x) + g2 * bf2f(u2.x) + g3 * bf2f(u3.x);
    acc.y = g0 * bf2f(a.y) + g1 * bf2f(u1.y) + g2 * bf2f(u2.y) + g3 * bf2f(u3.y);
    acc.z = g0 * bf2f(a.z) + g1 * bf2f(u1.z) + g2 * bf2f(u2.z) + g3 * bf2f(u3.z);
    acc.w = g0 * bf2f(a.w) + g1 * bf2f(u1.w) + g2 * bf2f(u2.w) + g3 * bf2f(u3.w);
    ushort4 r;
    r.x = f2bf(acc.x); r.y = f2bf(acc.y); r.z = f2bf(acc.z); r.w = f2bf(acc.w);
    ((ushort4*)dst)[i4] = r;
}

extern "C" void kernel_launch(void* const* d_in, const int* in_sizes, int n_in,
                              void* d_out, int out_size, void* d_ws, size_t ws_size,
                              hipStream_t stream) {
    const float* x       = (const float*)d_in[0];
    const float* em      = (const float*)d_in[1];
    const float* base_W0 = (const float*)d_in[2];
    const float* base_b0 = (const float*)d_in[3];
    const float* base_W1 = (const float*)d_in[4];
    const float* base_b1 = (const float*)d_in[5];
    const float* em_W0   = (const float*)d_in[6];
    const float* em_b0   = (const float*)d_in[7];
    const float* em_W1   = (const float*)d_in[8];
    const float* em_b1   = (const float*)d_in[9];
    const float* gate_W0 = (const float*)d_in[10];
    const float* gate_b0 = (const float*)d_in[11];
    const float* gate_W1 = (const float*)d_in[12];
    const float* gate_b1 = (const float*)d_in[13];
    const float* fc_W    = (const float*)d_in[14];
    const float* fc_b    = (const float*)d_in[15];
    const float* last_W  = (const float*)d_in[16];
    const float* last_b  = (const float*)d_in[17];

    const int H    = in_sizes[3];
    const int INF  = in_sizes[2] / H;
    const int B    = in_sizes[0] / INF;
    const int EMH  = in_sizes[7];
    const int GH   = in_sizes[11];
    const int GOUT = in_sizes[13];
    const int NOUT = in_sizes[17];

    float* out = (float*)d_out;
    float* o_final  = out;
    float* o_gates  = out + (size_t)B * NOUT;
    float* o_onehot = o_gates + (size_t)B * 10;
    float* o_soft   = o_onehot + (size_t)B * 10;

    const size_t szWT = (size_t)8 * H * H;
    const size_t szW0 = (size_t)2 * H * INF;
    const size_t szW1 = (size_t)2 * H * H;
    const size_t szWE = (size_t)2 * H * EMH;
    const size_t szWG = (size_t)2 * GH * H;
    const size_t fixed = szWT + 2 * (szW0 + szW1 + szWE + szWG);
    const size_t perRow = (size_t)10 * H + (size_t)4 * GH + 40;

    const bool shapesOK = (H % 256 == 0) && (GH % 128 == 0) &&
                          (INF % 64 == 0) && (EMH % 64 == 0);
    const bool useFast = shapesOK && (ws_size > fixed + 128 * perRow);
    const bool smallOK = (GOUT == 10) && (NOUT == 18) && (GH % 64 == 0) && (H % 64 == 0);

    char* wsb = (char*)d_ws;
    u16* WT  = (u16*)wsb;
    u16* W0h = (u16*)(wsb + szWT);
    u16* W0l = W0h + (size_t)H * INF;
    u16* W1h = (u16*)(wsb + szWT + 2 * szW0);
    u16* W1l = W1h + (size_t)H * H;
    u16* WEh = (u16*)(wsb + szWT + 2 * szW0 + 2 * szW1);
    u16* WEl = WEh + (size_t)H * EMH;
    u16* WGh = (u16*)(wsb + szWT + 2 * szW0 + 2 * szW1 + 2 * szWE);
    u16* WGl = WGh + (size_t)GH * H;

    int Bc = ((B + 127) / 128) * 128;
    size_t avail = ws_size - (useFast ? fixed : 0);
    while (Bc > 128 && (size_t)Bc * perRow > avail) Bc >>= 1;

    char* rows = wsb + (useFast ? fixed : 0);
    float* R0 = (float*)rows;
    float* R1 = (float*)(rows + (size_t)Bc * 4 * H);
    float* R2 = (float*)(rows + (size_t)Bc * 8 * H);
    u16*   RD = (u16*)(rows + (size_t)Bc * (8 * H + 4 * GH));
    float* LG = (float*)(rows + (size_t)Bc * (10 * H + 4 * GH));
    u16* O0 = (u16*)R0;
    u16* O1 = O0 + (size_t)Bc * H;
    u16* O2 = (u16*)R1;
    u16* O3 = O2 + (size_t)Bc * H;

    dim3 blk(256);
    const size_t fc1 = (size_t)H * H;

    if (useFast) {
        dim3 tg((unsigned)(H / 64), (unsigned)(H / 64));
        for (int i = 0; i < 4; ++i)
            transpose_kernel<<<tg, blk, 0, stream>>>(fc_W + (size_t)i * fc1, WT + (size_t)i * fc1, H, H);
        transpose_split_kernel<<<dim3((unsigned)(H / 64), (unsigned)(INF / 64)), blk, 0, stream>>>(
            base_W0, W0h, W0l, INF, H);
        transpose_split_kernel<<<dim3((unsigned)(H / 64), (unsigned)(H / 64)), blk, 0, stream>>>(
            base_W1, W1h, W1l, H, H);
        transpose_split_kernel<<<dim3((unsigned)(H / 64), (unsigned)(EMH / 64)), blk, 0, stream>>>(
            em_W1, WEh, WEl, EMH, H);
        transpose_split_kernel<<<dim3((unsigned)(GH / 64), (unsigned)(H / 64)), blk, 0, stream>>>(
            gate_W0, WGh, WGl, H, GH);
    }

    for (int c0 = 0; c0 < B; c0 += Bc) {
        const int Bcur = (B - c0 < Bc) ? (B - c0) : Bc;
        const float* xc  = x + (size_t)c0 * INF;
        const float* emc = em + c0;
        float* ofin = o_final  + (size_t)c0 * NOUT;
        float* ogat = o_gates  + (size_t)c0 * 10;
        float* ooh  = o_onehot + (size_t)c0 * 10;
        float* osf  = o_soft   + (size_t)c0 * 10;

        auto g64  = [&](int N) { return dim3((unsigned)((N + 63) / 64), (unsigned)((Bcur + 63) / 64)); };
        auto gS   = [&](int N) { return dim3((unsigned)(N / 128), (unsigned)((Bcur + 127) / 128)); };
        const dim3 mgrid((unsigned)(H / 256), (unsigned)((Bcur + 127) / 128));
        const int n4 = Bcur * H / 4;
        const dim3 cgrid((unsigned)((n4 + 255) / 256));
        const dim3 sgrid((unsigned)((Bcur + 15) / 16));

        // h0 = relu(x @ W0 + b0) -> R0
        mfma_split_kernel<0, true, false, false><<<gS(H), blk, 0, stream>>>(
            xc, nullptr, nullptr, nullptr, (const _Float16*)W0h, (const _Float16*)W0l,
            base_b0, nullptr, R0, nullptr, Bcur, H, INF);
        // base_out = h0 @ W1 + b1 -> R1 + RD = relu bf16
        mfma_split_kernel<0, false, false, true><<<gS(H), blk, 0, stream>>>(
            R0, nullptr, nullptr, nullptr, (const _Float16*)W1h, (const _Float16*)W1l,
            base_b1, nullptr, R1, RD, Bcur, H, H);
        // gate_in = relu(em-path @ em_W1 + em_b1) * base_out -> R0
        mfma_split_kernel<2, true, true, false><<<gS(H), blk, 0, stream>>>(
            nullptr, emc, em_W0, em_b0, (const _Float16*)WEh, (const _Float16*)WEl,
            em_b1, R1, R0, nullptr, Bcur, H, EMH);
        // g0 = relu(gate_in @ gate_W0 + gate_b0) -> R2
        mfma_split_kernel<0, true, false, false><<<gS(GH), blk, 0, stream>>>(
            R0, nullptr, nullptr, nullptr, (const _Float16*)WGh, (const _Float16*)WGl,
            gate_b0, nullptr, R2, nullptr, Bcur, GH, H);
        // logits -> LG
        if (smallOK) {
            smallN_kernel<10, false, false><<<sgrid, blk, (size_t)GH * 10 * 4, stream>>>(
                R2, gate_W1, gate_b1, LG, Bcur, GH);
        } else {
            gemm_kernel<0, false><<<g64(GOUT), blk, 0, stream>>>(
                R2, gate_W1, gate_b1, LG, Bcur, GOUT, GH);
        }
        routing_kernel<<<dim3((unsigned)((Bcur + 255) / 256)), blk, 0, stream>>>(LG, Bcur, ogat, ooh, osf);

        // fc chain (bf16 MFMA 128x256 tiles), combines fused
        mfma_fc_kernel<0><<<mgrid, blk, 0, stream>>>(
            (const short*)RD, nullptr, nullptr, nullptr, 0,
            (const short*)WT, fc_b, (short*)O0, Bcur, H, H);
        mfma_fc_kernel<0><<<mgrid, blk, 0, stream>>>(
            (const short*)O0, nullptr, nullptr, nullptr, 0,
            (const short*)(WT + fc1), fc_b + H, (short*)O1, Bcur, H, H);
        mfma_fc_kernel<1><<<mgrid, blk, 0, stream>>>(
            (const short*)O0, (const short*)O1, nullptr, ogat, 1,
            (const short*)(WT + 2 * fc1), fc_b + 2 * H, (short*)O2, Bcur, H, H);
        mfma_fc_kernel<2><<<mgrid, blk, 0, stream>>>(
            (const short*)O0, (const short*)O1, (const short*)O2, ogat, 3,
            (const short*)(WT + 3 * fc1), fc_b + 3 * H, (short*)O3, Bcur, H, H);

        combine_kernel<<<cgrid, blk, 0, stream>>>(ogat, 6, n4, H, O0, O1, O2, O3, RD);
        if (smallOK) {
            smallN_kernel<18, true, true><<<sgrid, blk, (size_t)H * 18 * 2, stream>>>(
                RD, last_W, last_b, ofin, Bcur, H);
        } else {
            gemm_kernel<1, false><<<g64(NOUT), blk, 0, stream>>>(
                RD, last_W, last_b, (void*)ofin, Bcur, NOUT, H);
        }
    }
}

// Round 15
// 555.173 us; speedup vs baseline: 1.0757x; 1.0757x over previous
//
#include <hip/hip_runtime.h>
#include <hip/hip_bf16.h>

// DepthRouteNet — round 15: revert fc to 128x128 (R14's 128x256 = 256 blocks =
// 1/CU, parallelism collapse). Add global_load_lds width-16 B staging to the fc
// kernel: B lands in [seg][row] chunk order (conflict-free frag reads), A stays
// VGPR-staged (fused combine) in padded-40 layout.

typedef unsigned short u16;
typedef __attribute__((ext_vector_type(8))) short bf16x8;
typedef _Float16 f16x8 __attribute__((ext_vector_type(8)));
typedef __attribute__((ext_vector_type(4))) float f32x4;

typedef const __attribute__((address_space(1))) void* gas_ptr;
typedef __attribute__((address_space(3))) void* las_ptr;

__device__ inline float bf2f(u16 u) {
    union { unsigned int i; float f; } v; v.i = ((unsigned int)u) << 16; return v.f;
}
__device__ inline u16 f2bf(float f) {
    union { float f; unsigned int i; } v; v.f = f;
    unsigned int x = v.i;
    return (u16)((x + 0x7FFFu + ((x >> 16) & 1u)) >> 16);   // RNE
}

// ---------------- split-f16 MFMA GEMM (routing path; unchanged R13) ----------
template<int AMODE, bool RELU_OUT, bool MUL_EPI, bool DUAL>
__global__ __launch_bounds__(256, 2) void mfma_split_kernel(
    const float* __restrict__ A, const float* __restrict__ emp,
    const float* __restrict__ emW0, const float* __restrict__ emb0,
    const _Float16* __restrict__ BTh, const _Float16* __restrict__ BTl,
    const float* __restrict__ bias, const float* __restrict__ MulM,
    float* __restrict__ C, u16* __restrict__ Drelu, int M, int N, int K)
{
    __shared__ _Float16 Ah[128 * 40], Al[128 * 40];
    __shared__ _Float16 Bh[128 * 40], Bl[128 * 40];

    const int tid = threadIdx.x;
    const int wave = tid >> 6, lane = tid & 63;
    const int id = blockIdx.y * gridDim.x + blockIdx.x;
    const int nM = gridDim.y;
    const int m0 = (id % nM) * 128, n0 = (id / nM) * 128;
    const int quad = lane >> 4, l16 = lane & 15;
    const int mq = (wave >> 1) * 64, nq = (wave & 1) * 64;

    const int srow = tid >> 1;
    const int shf  = (tid & 1) * 16;

    f32x4 acch[4][4] = {};
    f32x4 accl[4][4] = {};

    for (int k0 = 0; k0 < K; k0 += 32) {
        {
            int ra = m0 + srow; if (ra >= M) ra = M - 1;
            float v[16];
            if constexpr (AMODE == 0) {
#pragma unroll
                for (int s = 0; s < 4; ++s) {
                    float4 q = *(const float4*)&A[(size_t)ra * K + k0 + shf + s * 4];
                    v[s*4+0] = q.x; v[s*4+1] = q.y; v[s*4+2] = q.z; v[s*4+3] = q.w;
                }
            } else {
                float emv = emp[ra];
#pragma unroll
                for (int s = 0; s < 4; ++s) {
                    float4 w = *(const float4*)&emW0[k0 + shf + s * 4];
                    float4 b = *(const float4*)&emb0[k0 + shf + s * 4];
                    v[s*4+0] = fmaxf(emv * w.x + b.x, 0.f);
                    v[s*4+1] = fmaxf(emv * w.y + b.y, 0.f);
                    v[s*4+2] = fmaxf(emv * w.z + b.z, 0.f);
                    v[s*4+3] = fmaxf(emv * w.w + b.w, 0.f);
                }
            }
            f16x8 h0, h1, l0, l1;
#pragma unroll
            for (int e = 0; e < 8; ++e) {
                _Float16 h = (_Float16)v[e];
                h0[e] = h; l0[e] = (_Float16)((v[e] - (float)h) * 2048.0f);
            }
#pragma unroll
            for (int e = 0; e < 8; ++e) {
                _Float16 h = (_Float16)v[8 + e];
                h1[e] = h; l1[e] = (_Float16)((v[8 + e] - (float)h) * 2048.0f);
            }
            *(f16x8*)&Ah[srow * 40 + shf]     = h0;
            *(f16x8*)&Ah[srow * 40 + shf + 8] = h1;
            *(f16x8*)&Al[srow * 40 + shf]     = l0;
            *(f16x8*)&Al[srow * 40 + shf + 8] = l1;
        }
        {
            size_t boff = (size_t)(n0 + srow) * K + k0 + shf;
            *(f16x8*)&Bh[srow * 40 + shf]     = *(const f16x8*)&BTh[boff];
            *(f16x8*)&Bh[srow * 40 + shf + 8] = *(const f16x8*)&BTh[boff + 8];
            *(f16x8*)&Bl[srow * 40 + shf]     = *(const f16x8*)&BTl[boff];
            *(f16x8*)&Bl[srow * 40 + shf + 8] = *(const f16x8*)&BTl[boff + 8];
        }
        __syncthreads();

        f16x8 afh[4], afl[4], bfh[4], bfl[4];
#pragma unroll
        for (int i = 0; i < 4; ++i) {
            afh[i] = *(const f16x8*)&Ah[(mq + i * 16 + l16) * 40 + quad * 8];
            afl[i] = *(const f16x8*)&Al[(mq + i * 16 + l16) * 40 + quad * 8];
        }
#pragma unroll
        for (int j = 0; j < 4; ++j) {
            bfh[j] = *(const f16x8*)&Bh[(nq + j * 16 + l16) * 40 + quad * 8];
            bfl[j] = *(const f16x8*)&Bl[(nq + j * 16 + l16) * 40 + quad * 8];
        }
#pragma unroll
        for (int i = 0; i < 4; ++i)
#pragma unroll
            for (int j = 0; j < 4; ++j) {
                acch[i][j] = __builtin_amdgcn_mfma_f32_16x16x32_f16(afh[i], bfh[j], acch[i][j], 0, 0, 0);
                accl[i][j] = __builtin_amdgcn_mfma_f32_16x16x32_f16(afh[i], bfl[j], accl[i][j], 0, 0, 0);
                accl[i][j] = __builtin_amdgcn_mfma_f32_16x16x32_f16(afl[i], bfh[j], accl[i][j], 0, 0, 0);
            }
        __syncthreads();
    }

    const float S = 1.0f / 2048.0f;
#pragma unroll
    for (int i = 0; i < 4; ++i) {
#pragma unroll
        for (int j = 0; j < 4; ++j) {
            int col = n0 + nq + j * 16 + l16;
            float bv = bias[col];
#pragma unroll
            for (int r = 0; r < 4; ++r) {
                int row = m0 + mq + i * 16 + quad * 4 + r;
                if (row < M) {
                    float v = acch[i][j][r] + accl[i][j][r] * S + bv;
                    if (RELU_OUT) v = fmaxf(v, 0.f);
                    if (MUL_EPI)  v *= MulM[(size_t)row * N + col];
                    C[(size_t)row * N + col] = v;
                    if (DUAL) Drelu[(size_t)row * N + col] = f2bf(fmaxf(v, 0.f));
                }
            }
        }
    }
}

// ---------------- MFMA bf16 GEMM for fc layers: 128x128, B via direct-LDS ----
// B staged with global_load_lds w=16 into [seg][row] chunk order: slot c ->
// (row=c&127, seg=c>>7); frag read addr (quad*128+row)*16B -> 2-way only.
// CMODE: 0 plain; 1 g0*A+g1*o1; 2 +g2*o2
template<int CMODE>
__global__ __launch_bounds__(256) void mfma_fc_kernel(
    const short* __restrict__ A, const short* __restrict__ o1p,
    const short* __restrict__ o2p, const float* __restrict__ gates, int goff,
    const short* __restrict__ BT, const float* __restrict__ bias,
    short* __restrict__ C, int M, int N, int K)
{
    __shared__ short As[128 * 40];   // padded [row][seg]
    __shared__ short Bs[512 * 8];    // [seg][row] chunks, 8 KB unpadded
    const int tid = threadIdx.x;
    const int wave = tid >> 6, lane = tid & 63;
    const int id = blockIdx.y * gridDim.x + blockIdx.x;
    const int nM = gridDim.y;
    const int m0 = (id % nM) * 128, n0 = (id / nM) * 128;
    const int quad = lane >> 4, l16 = lane & 15;
    const int mq = (wave >> 1) * 64, nq = (wave & 1) * 64;

    f32x4 acc[4][4] = {};

    for (int k0 = 0; k0 < K; k0 += 32) {
        // ---- B: async direct-to-LDS, 2 calls/wave, 16B/lane ----
#pragma unroll
        for (int a = 0; a < 2; ++a) {
            int c = a * 256 + wave * 64 + lane;
            int row = c & 127, seg = c >> 7;
            const short* gp = &BT[(size_t)(n0 + row) * K + k0 + seg * 8];
            __builtin_amdgcn_global_load_lds(
                (gas_ptr)(const void*)gp,
                (las_ptr)(void*)&Bs[(size_t)(a * 256 + wave * 64) * 8],
                16, 0, 0);
        }
        // ---- A: VGPR staging (fused combine) into padded LDS ----
#pragma unroll
        for (int it = 0; it < 2; ++it) {
            int c = it * 256 + tid;
            int row = c >> 2, seg = c & 3;
            int ra = m0 + row; if (ra >= M) ra = M - 1;
            bf16x8 va = *(const bf16x8*)&A[(size_t)ra * K + k0 + seg * 8];
            if constexpr (CMODE > 0) {
                const float* gp = gates + (size_t)ra * 10 + goff;
                float g0 = gp[0], g1 = gp[1];
                bf16x8 v1 = *(const bf16x8*)&o1p[(size_t)ra * K + k0 + seg * 8];
                float g2 = 0.f; bf16x8 v2;
                if constexpr (CMODE == 2) {
                    g2 = gp[2];
                    v2 = *(const bf16x8*)&o2p[(size_t)ra * K + k0 + seg * 8];
                }
#pragma unroll
                for (int e = 0; e < 8; ++e) {
                    float f = g0 * bf2f((u16)va[e]) + g1 * bf2f((u16)v1[e]);
                    if constexpr (CMODE == 2) f += g2 * bf2f((u16)v2[e]);
                    va[e] = (short)f2bf(f);
                }
            }
            *(bf16x8*)&As[row * 40 + seg * 8] = va;
        }
        __syncthreads();

        bf16x8 af[4], bfr[4];
#pragma unroll
        for (int i = 0; i < 4; ++i)
            af[i] = *(const bf16x8*)&As[(mq + i * 16 + l16) * 40 + quad * 8];
#pragma unroll
        for (int j = 0; j < 4; ++j)
            bfr[j] = *(const bf16x8*)&Bs[(size_t)(quad * 128 + nq + j * 16 + l16) * 8];
#pragma unroll
        for (int i = 0; i < 4; ++i)
#pragma unroll
            for (int j = 0; j < 4; ++j)
                acc[i][j] = __builtin_amdgcn_mfma_f32_16x16x32_bf16(af[i], bfr[j], acc[i][j], 0, 0, 0);
        __syncthreads();
    }

#pragma unroll
    for (int i = 0; i < 4; ++i) {
#pragma unroll
        for (int j = 0; j < 4; ++j) {
            int col = n0 + nq + j * 16 + l16;
            float bv = bias[col];
#pragma unroll
            for (int r = 0; r < 4; ++r) {
                int row = m0 + mq + i * 16 + quad * 4 + r;
                if (row < M) {
                    float v = fmaxf(acc[i][j][r] + bv, 0.f);
                    C[(size_t)row * N + col] = (short)f2bf(v);
                }
            }
        }
    }
}

// ---------------- small-N GEMM (logits N=10, final N=18) ---------------------
template<int NN, bool ABF16, bool BBF16>
__global__ __launch_bounds__(256) void smallN_kernel(
    const void* __restrict__ Av, const float* __restrict__ Bw,
    const float* __restrict__ bias, float* __restrict__ C, int M, int K)
{
    extern __shared__ char smem[];
    const int tid = threadIdx.x;
    const int total = K * NN;
    if (BBF16) {
        u16* Bs = (u16*)smem;
        for (int i = tid; i < total; i += 256) Bs[i] = f2bf(Bw[i]);
    } else {
        float* Bs = (float*)smem;
        for (int i = tid; i < total; i += 256) Bs[i] = Bw[i];
    }
    __syncthreads();

    const int lane = tid & 63;
    const int wave = tid >> 6;
    const int l16 = lane & 15;
    const int rsub = lane >> 4;
    int row = blockIdx.x * 16 + wave * 4 + rsub;
    const bool valid = (row < M);
    if (row >= M) row = M - 1;

    float acc[NN];
#pragma unroll
    for (int j = 0; j < NN; ++j) acc[j] = 0.f;

    const int chunk = K >> 4;
    const int kbeg = l16 * chunk;

    if (ABF16) {
        const u16* A = (const u16*)Av + (size_t)row * K + kbeg;
        const u16* Bs = (const u16*)smem;
        for (int kk = 0; kk < chunk; kk += 4) {
            ushort4 u = *(const ushort4*)&A[kk];
            float a4[4] = {bf2f(u.x), bf2f(u.y), bf2f(u.z), bf2f(u.w)};
#pragma unroll
            for (int e = 0; e < 4; ++e) {
                const u16* bp = &Bs[(size_t)(kbeg + kk + e) * NN];
#pragma unroll
                for (int j = 0; j < NN; ++j) acc[j] += a4[e] * bf2f(bp[j]);
            }
        }
    } else {
        const float* A = (const float*)Av + (size_t)row * K + kbeg;
        const float* Bs = (const float*)smem;
        for (int kk = 0; kk < chunk; kk += 4) {
            float4 q = *(const float4*)&A[kk];
            float a4[4] = {q.x, q.y, q.z, q.w};
#pragma unroll
            for (int e = 0; e < 4; ++e) {
                const float* bp = &Bs[(size_t)(kbeg + kk + e) * NN];
#pragma unroll
                for (int j = 0; j < NN; ++j) acc[j] += a4[e] * bp[j];
            }
        }
    }

#pragma unroll
    for (int j = 0; j < NN; ++j) {
        float v = acc[j];
        v += __shfl_xor(v, 1, 16);
        v += __shfl_xor(v, 2, 16);
        v += __shfl_xor(v, 4, 16);
        v += __shfl_xor(v, 8, 16);
        acc[j] = v;
    }
    if (valid && l16 == 0) {
#pragma unroll
        for (int j = 0; j < NN; ++j)
            C[(size_t)row * NN + j] = acc[j] + bias[j];
    }
}

// ---------------- f32 64-tile GEMM (fallback) --------------------------------
template<int AMODE, bool OUT_BF16>
__global__ __launch_bounds__(256) void gemm_kernel(
    const void* __restrict__ Av, const float* __restrict__ Bw,
    const float* __restrict__ bias, void* __restrict__ Cv, int M, int N, int K)
{
    __shared__ float As[16][68];
    __shared__ float Bs[16][64];

    const int tid = threadIdx.x;
    const int tx = tid & 15, ty = tid >> 4;
    const int m0 = blockIdx.y * 64;
    const int n0 = blockIdx.x * 64;

    const int arow = tid >> 2;
    const int ak   = (tid & 3) * 4;
    const int brow = tid >> 4;
    const int bcol = (tid & 15) * 4;

    float acc[4][4];
#pragma unroll
    for (int i = 0; i < 4; i++)
#pragma unroll
        for (int j = 0; j < 4; j++) acc[i][j] = 0.f;

    for (int k0 = 0; k0 < K; k0 += 16) {
        float4 av;
        int r = m0 + arow; if (r >= M) r = M - 1;
        if constexpr (AMODE == 0) {
            av = *(const float4*)((const float*)Av + (size_t)r * K + (k0 + ak));
        } else {
            ushort4 u = *(const ushort4*)((const u16*)Av + (size_t)r * K + (k0 + ak));
            av.x = bf2f(u.x); av.y = bf2f(u.y); av.z = bf2f(u.z); av.w = bf2f(u.w);
        }
        As[ak + 0][arow] = av.x; As[ak + 1][arow] = av.y;
        As[ak + 2][arow] = av.z; As[ak + 3][arow] = av.w;

#pragma unroll
        for (int j = 0; j < 4; j++) {
            int c = n0 + bcol + j;
            Bs[brow][bcol + j] = (c < N) ? Bw[(size_t)(k0 + brow) * N + c] : 0.f;
        }
        __syncthreads();

#pragma unroll
        for (int kk = 0; kk < 16; kk++) {
            float4 a = *(const float4*)&As[kk][ty * 4];
            float4 b = *(const float4*)&Bs[kk][tx * 4];
            acc[0][0] += a.x * b.x; acc[0][1] += a.x * b.y; acc[0][2] += a.x * b.z; acc[0][3] += a.x * b.w;
            acc[1][0] += a.y * b.x; acc[1][1] += a.y * b.y; acc[1][2] += a.y * b.z; acc[1][3] += a.y * b.w;
            acc[2][0] += a.z * b.x; acc[2][1] += a.z * b.y; acc[2][2] += a.z * b.z; acc[2][3] += a.z * b.w;
            acc[3][0] += a.w * b.x; acc[3][1] += a.w * b.y; acc[3][2] += a.w * b.z; acc[3][3] += a.w * b.w;
        }
        __syncthreads();
    }

#pragma unroll
    for (int i = 0; i < 4; i++) {
        int r = m0 + ty * 4 + i;
#pragma unroll
        for (int j = 0; j < 4; j++) {
            int c = n0 + tx * 4 + j;
            if (r < M && c < N) {
                float v = acc[i][j] + bias[c];
                if (OUT_BF16) ((u16*)Cv)[(size_t)r * N + c] = f2bf(v);
                else          ((float*)Cv)[(size_t)r * N + c] = v;
            }
        }
    }
}

// transpose + f32->bf16: in [K,N] f32 -> out [N,K] bf16. K,N % 64 == 0.
__global__ __launch_bounds__(256) void transpose_kernel(
    const float* __restrict__ in, u16* __restrict__ out, int K, int N)
{
    __shared__ u16 T[64][65];
    int k0 = blockIdx.y * 64, n0 = blockIdx.x * 64;
    int t = threadIdx.x;
    int r = t >> 4, c4 = (t & 15) * 4;
#pragma unroll
    for (int i = 0; i < 4; ++i) {
        int kk = r + i * 16;
        float4 v = *(const float4*)&in[(size_t)(k0 + kk) * N + n0 + c4];
        T[c4 + 0][kk] = f2bf(v.x); T[c4 + 1][kk] = f2bf(v.y);
        T[c4 + 2][kk] = f2bf(v.z); T[c4 + 3][kk] = f2bf(v.w);
    }
    __syncthreads();
#pragma unroll
    for (int i = 0; i < 4; ++i) {
        int nn = r + i * 16;
        ushort4 o;
        o.x = T[nn][c4 + 0]; o.y = T[nn][c4 + 1];
        o.z = T[nn][c4 + 2]; o.w = T[nn][c4 + 3];
        *(ushort4*)&out[(size_t)(n0 + nn) * K + k0 + c4] = o;
    }
}

// transpose + f16 hi/lo split: in [K,N] f32 -> hi/lo f16 [N,K]. K,N % 64 == 0.
__global__ __launch_bounds__(256) void transpose_split_kernel(
    const float* __restrict__ in, u16* __restrict__ outh, u16* __restrict__ outl,
    int K, int N)
{
    __shared__ u16 Th[64][65];
    __shared__ u16 Tl[64][65];
    int k0 = blockIdx.y * 64, n0 = blockIdx.x * 64;
    int t = threadIdx.x;
    int r = t >> 4, c4 = (t & 15) * 4;
    union { _Float16 h; u16 u; } cv;
#pragma unroll
    for (int i = 0; i < 4; ++i) {
        int kk = r + i * 16;
        float4 v = *(const float4*)&in[(size_t)(k0 + kk) * N + n0 + c4];
        float vv[4] = {v.x, v.y, v.z, v.w};
#pragma unroll
        for (int e = 0; e < 4; ++e) {
            _Float16 h = (_Float16)vv[e];
            cv.h = h; Th[c4 + e][kk] = cv.u;
            cv.h = (_Float16)((vv[e] - (float)h) * 2048.0f);
            Tl[c4 + e][kk] = cv.u;
        }
    }
    __syncthreads();
#pragma unroll
    for (int i = 0; i < 4; ++i) {
        int nn = r + i * 16;
        ushort4 oh, ol;
        oh.x = Th[nn][c4 + 0]; oh.y = Th[nn][c4 + 1];
        oh.z = Th[nn][c4 + 2]; oh.w = Th[nn][c4 + 3];
        ol.x = Tl[nn][c4 + 0]; ol.y = Tl[nn][c4 + 1];
        ol.z = Tl[nn][c4 + 2]; ol.w = Tl[nn][c4 + 3];
        *(ushort4*)&outh[(size_t)(n0 + nn) * K + k0 + c4] = oh;
        *(ushort4*)&outl[(size_t)(n0 + nn) * K + k0 + c4] = ol;
    }
}

__global__ __launch_bounds__(256) void routing_kernel(
    const float* __restrict__ logits, int Bc,
    float* __restrict__ gates, float* __restrict__ onehot,
    float* __restrict__ soft)
{
    int b = blockIdx.x * blockDim.x + threadIdx.x;
    if (b >= Bc) return;
    const float* l = logits + (size_t)b * 10;
    float* g  = gates  + (size_t)b * 10;
    float* oh = onehot + (size_t)b * 10;
    float* sf = soft   + (size_t)b * 10;

    g[0] = 1.f; oh[0] = 1.f; sf[0] = 1.f;

    int off = 1;
    for (int m = 2; m <= 4; m++) {
        float v[4];
        for (int i = 0; i < m; i++) v[i] = l[off + i];
        int i0 = 0;
        for (int i = 1; i < m; i++) if (v[i] > v[i0]) i0 = i;
        int i1 = (i0 == 0) ? 1 : 0;
        for (int i = 0; i < m; i++) if (i != i0 && v[i] > v[i1]) i1 = i;
        float e1 = expf(v[i1] - v[i0]);
        float inv = 1.f / (1.f + e1);
        for (int i = 0; i < m; i++) { g[off + i] = 0.f; oh[off + i] = 0.f; }
        g[off + i0] = inv;
        g[off + i1] = e1 * inv;
        oh[off + i0] = 1.f; oh[off + i1] = 1.f;
        float mall = v[0];
        for (int i = 1; i < m; i++) mall = fmaxf(mall, v[i]);
        float ex[4]; float se = 0.f;
        for (int i = 0; i < m; i++) { ex[i] = expf(v[i] - mall); se += ex[i]; }
        float rse = 1.f / se;
        for (int i = 0; i < m; i++) sf[off + i] = ex[i] * rse;
        off += m;
    }
}

__global__ __launch_bounds__(256) void combine_kernel(
    const float* __restrict__ gates, int goff, int n4, int H,
    const u16* __restrict__ o0, const u16* __restrict__ o1,
    const u16* __restrict__ o2, const u16* __restrict__ o3,
    u16* __restrict__ dst)
{
    int i4 = blockIdx.x * blockDim.x + threadIdx.x;
    if (i4 >= n4) return;
    int b = (i4 * 4) / H;
    const float* gp = gates + (size_t)b * 10 + goff;
    float g0 = gp[0], g1 = gp[1], g2 = gp[2], g3 = gp[3];
    ushort4 a  = ((const ushort4*)o0)[i4];
    ushort4 u1 = ((const ushort4*)o1)[i4];
    ushort4 u2 = ((const ushort4*)o2)[i4];
    ushort4 u3 = ((const ushort4*)o3)[i4];
    float4 acc;
    acc.x = g0 * bf2f(a.x) + g1 * bf2f(u1.x) + g2 * bf2f(u2.x) + g3 * bf2f(u3.x);
    acc.y = g0 * bf2f(a.y) + g1 * bf2f(u1.y) + g2 * bf2f(u2.y) + g3 * bf2f(u3.y);
    acc.z = g0 * bf2f(a.z) + g1 * bf2f(u1.z) + g2 * bf2f(u2.z) + g3 * bf2f(u3.z);
    acc.w = g0 * bf2f(a.w) + g1 * bf2f(u1.w) + g2 * bf2f(u2.w) + g3 * bf2f(u3.w);
    ushort4 r;
    r.x = f2bf(acc.x); r.y = f2bf(acc.y); r.z = f2bf(acc.z); r.w = f2bf(acc.w);
    ((ushort4*)dst)[i4] = r;
}

extern "C" void kernel_launch(void* const* d_in, const int* in_sizes, int n_in,
                              void* d_out, int out_size, void* d_ws, size_t ws_size,
                              hipStream_t stream) {
    const float* x       = (const float*)d_in[0];
    const float* em      = (const float*)d_in[1];
    const float* base_W0 = (const float*)d_in[2];
    const float* base_b0 = (const float*)d_in[3];
    const float* base_W1 = (const float*)d_in[4];
    const float* base_b1 = (const float*)d_in[5];
    const float* em_W0   = (const float*)d_in[6];
    const float* em_b0   = (const float*)d_in[7];
    const float* em_W1   = (const float*)d_in[8];
    const float* em_b1   = (const float*)d_in[9];
    const float* gate_W0 = (const float*)d_in[10];
    const float* gate_b0 = (const float*)d_in[11];
    const float* gate_W1 = (const float*)d_in[12];
    const float* gate_b1 = (const float*)d_in[13];
    const float* fc_W    = (const float*)d_in[14];
    const float* fc_b    = (const float*)d_in[15];
    const float* last_W  = (const float*)d_in[16];
    const float* last_b  = (const float*)d_in[17];

    const int H    = in_sizes[3];
    const int INF  = in_sizes[2] / H;
    const int B    = in_sizes[0] / INF;
    const int EMH  = in_sizes[7];
    const int GH   = in_sizes[11];
    const int GOUT = in_sizes[13];
    const int NOUT = in_sizes[17];

    float* out = (float*)d_out;
    float* o_final  = out;
    float* o_gates  = out + (size_t)B * NOUT;
    float* o_onehot = o_gates + (size_t)B * 10;
    float* o_soft   = o_onehot + (size_t)B * 10;

    const size_t szWT = (size_t)8 * H * H;
    const size_t szW0 = (size_t)2 * H * INF;
    const size_t szW1 = (size_t)2 * H * H;
    const size_t szWE = (size_t)2 * H * EMH;
    const size_t szWG = (size_t)2 * GH * H;
    const size_t fixed = szWT + 2 * (szW0 + szW1 + szWE + szWG);
    const size_t perRow = (size_t)10 * H + (size_t)4 * GH + 40;

    const bool shapesOK = (H % 128 == 0) && (GH % 128 == 0) &&
                          (INF % 64 == 0) && (EMH % 64 == 0);
    const bool useFast = shapesOK && (ws_size > fixed + 128 * perRow);
    const bool smallOK = (GOUT == 10) && (NOUT == 18) && (GH % 64 == 0) && (H % 64 == 0);

    char* wsb = (char*)d_ws;
    u16* WT  = (u16*)wsb;
    u16* W0h = (u16*)(wsb + szWT);
    u16* W0l = W0h + (size_t)H * INF;
    u16* W1h = (u16*)(wsb + szWT + 2 * szW0);
    u16* W1l = W1h + (size_t)H * H;
    u16* WEh = (u16*)(wsb + szWT + 2 * szW0 + 2 * szW1);
    u16* WEl = WEh + (size_t)H * EMH;
    u16* WGh = (u16*)(wsb + szWT + 2 * szW0 + 2 * szW1 + 2 * szWE);
    u16* WGl = WGh + (size_t)GH * H;

    int Bc = ((B + 127) / 128) * 128;
    size_t avail = ws_size - (useFast ? fixed : 0);
    while (Bc > 128 && (size_t)Bc * perRow > avail) Bc >>= 1;

    char* rows = wsb + (useFast ? fixed : 0);
    float* R0 = (float*)rows;
    float* R1 = (float*)(rows + (size_t)Bc * 4 * H);
    float* R2 = (float*)(rows + (size_t)Bc * 8 * H);
    u16*   RD = (u16*)(rows + (size_t)Bc * (8 * H + 4 * GH));
    float* LG = (float*)(rows + (size_t)Bc * (10 * H + 4 * GH));
    u16* O0 = (u16*)R0;
    u16* O1 = O0 + (size_t)Bc * H;
    u16* O2 = (u16*)R1;
    u16* O3 = O2 + (size_t)Bc * H;

    dim3 blk(256);
    const size_t fc1 = (size_t)H * H;

    if (useFast) {
        dim3 tg((unsigned)(H / 64), (unsigned)(H / 64));
        for (int i = 0; i < 4; ++i)
            transpose_kernel<<<tg, blk, 0, stream>>>(fc_W + (size_t)i * fc1, WT + (size_t)i * fc1, H, H);
        transpose_split_kernel<<<dim3((unsigned)(H / 64), (unsigned)(INF / 64)), blk, 0, stream>>>(
            base_W0, W0h, W0l, INF, H);
        transpose_split_kernel<<<dim3((unsigned)(H / 64), (unsigned)(H / 64)), blk, 0, stream>>>(
            base_W1, W1h, W1l, H, H);
        transpose_split_kernel<<<dim3((unsigned)(H / 64), (unsigned)(EMH / 64)), blk, 0, stream>>>(
            em_W1, WEh, WEl, EMH, H);
        transpose_split_kernel<<<dim3((unsigned)(GH / 64), (unsigned)(H / 64)), blk, 0, stream>>>(
            gate_W0, WGh, WGl, H, GH);
    }

    for (int c0 = 0; c0 < B; c0 += Bc) {
        const int Bcur = (B - c0 < Bc) ? (B - c0) : Bc;
        const float* xc  = x + (size_t)c0 * INF;
        const float* emc = em + c0;
        float* ofin = o_final  + (size_t)c0 * NOUT;
        float* ogat = o_gates  + (size_t)c0 * 10;
        float* ooh  = o_onehot + (size_t)c0 * 10;
        float* osf  = o_soft   + (size_t)c0 * 10;

        auto g64  = [&](int N) { return dim3((unsigned)((N + 63) / 64), (unsigned)((Bcur + 63) / 64)); };
        auto gS   = [&](int N) { return dim3((unsigned)(N / 128), (unsigned)((Bcur + 127) / 128)); };
        const dim3 mgrid((unsigned)(H / 128), (unsigned)((Bcur + 127) / 128));
        const int n4 = Bcur * H / 4;
        const dim3 cgrid((unsigned)((n4 + 255) / 256));
        const dim3 sgrid((unsigned)((Bcur + 15) / 16));

        // h0 = relu(x @ W0 + b0) -> R0
        mfma_split_kernel<0, true, false, false><<<gS(H), blk, 0, stream>>>(
            xc, nullptr, nullptr, nullptr, (const _Float16*)W0h, (const _Float16*)W0l,
            base_b0, nullptr, R0, nullptr, Bcur, H, INF);
        // base_out = h0 @ W1 + b1 -> R1 + RD = relu bf16
        mfma_split_kernel<0, false, false, true><<<gS(H), blk, 0, stream>>>(
            R0, nullptr, nullptr, nullptr, (const _Float16*)W1h, (const _Float16*)W1l,
            base_b1, nullptr, R1, RD, Bcur, H, H);
        // gate_in = relu(em-path @ em_W1 + em_b1) * base_out -> R0
        mfma_split_kernel<2, true, true, false><<<gS(H), blk, 0, stream>>>(
            nullptr, emc, em_W0, em_b0, (const _Float16*)WEh, (const _Float16*)WEl,
            em_b1, R1, R0, nullptr, Bcur, H, EMH);
        // g0 = relu(gate_in @ gate_W0 + gate_b0) -> R2
        mfma_split_kernel<0, true, false, false><<<gS(GH), blk, 0, stream>>>(
            R0, nullptr, nullptr, nullptr, (const _Float16*)WGh, (const _Float16*)WGl,
            gate_b0, nullptr, R2, nullptr, Bcur, GH, H);
        // logits -> LG
        if (smallOK) {
            smallN_kernel<10, false, false><<<sgrid, blk, (size_t)GH * 10 * 4, stream>>>(
                R2, gate_W1, gate_b1, LG, Bcur, GH);
        } else {
            gemm_kernel<0, false><<<g64(GOUT), blk, 0, stream>>>(
                R2, gate_W1, gate_b1, LG, Bcur, GOUT, GH);
        }
        routing_kernel<<<dim3((unsigned)((Bcur + 255) / 256)), blk, 0, stream>>>(LG, Bcur, ogat, ooh, osf);

        // fc chain (bf16 MFMA 128x128, B via global_load_lds), combines fused
        mfma_fc_kernel<0><<<mgrid, blk, 0, stream>>>(
            (const short*)RD, nullptr, nullptr, nullptr, 0,
            (const short*)WT, fc_b, (short*)O0, Bcur, H, H);
        mfma_fc_kernel<0><<<mgrid, blk, 0, stream>>>(
            (const short*)O0, nullptr, nullptr, nullptr, 0,
            (const short*)(WT + fc1), fc_b + H, (short*)O1, Bcur, H, H);
        mfma_fc_kernel<1><<<mgrid, blk, 0, stream>>>(
            (const short*)O0, (const short*)O1, nullptr, ogat, 1,
            (const short*)(WT + 2 * fc1), fc_b + 2 * H, (short*)O2, Bcur, H, H);
        mfma_fc_kernel<2><<<mgrid, blk, 0, stream>>>(
            (const short*)O0, (const short*)O1, (const short*)O2, ogat, 3,
            (const short*)(WT + 3 * fc1), fc_b + 3 * H, (short*)O3, Bcur, H, H);

        combine_kernel<<<cgrid, blk, 0, stream>>>(ogat, 6, n4, H, O0, O1, O2, O3, RD);
        if (smallOK) {
            smallN_kernel<18, true, true><<<sgrid, blk, (size_t)H * 18 * 2, stream>>>(
                RD, last_W, last_b, ofin, Bcur, H);
        } else {
            gemm_kernel<1, false><<<g64(NOUT), blk, 0, stream>>>(
                RD, last_W, last_b, (void*)ofin, Bcur, NOUT, H);
        }
    }
}